// Round 3
// baseline (323.431 us; speedup 1.0000x reference)
//
#include <hip/hip_runtime.h>
#include <hip/hip_bf16.h>
#include <stdint.h>

typedef __attribute__((ext_vector_type(8))) short short8;           // 8 bf16 (4 VGPR) MFMA frag
typedef __attribute__((ext_vector_type(4))) float f32x4;            // MFMA acc
typedef __attribute__((ext_vector_type(4))) unsigned short ushort4_t;
typedef __attribute__((ext_vector_type(8))) unsigned short ushort8_t;

#define K_TOT 4096
#define N_TOT 4096

static __device__ __forceinline__ unsigned short f2bf(float f) {
    union { float f; unsigned int u; } v; v.f = f;
    unsigned int u = v.u;
    u += 0x7fffu + ((u >> 16) & 1u);   // round-to-nearest-even
    return (unsigned short)(u >> 16);
}

// ---------------- prepass: x fp32 -> bf16 -------------------------------------------
__global__ void cvt_x_kernel(const float4* __restrict__ x, ushort8_t* __restrict__ out, long n8) {
    long i = (long)blockIdx.x * blockDim.x + threadIdx.x;
    long stride = (long)gridDim.x * blockDim.x;
    for (; i < n8; i += stride) {
        float4 a = x[2 * i], b = x[2 * i + 1];
        ushort8_t r;
        r[0] = f2bf(a.x); r[1] = f2bf(a.y); r[2] = f2bf(a.z); r[3] = f2bf(a.w);
        r[4] = f2bf(b.x); r[5] = f2bf(b.y); r[6] = f2bf(b.z); r[7] = f2bf(b.w);
        out[i] = r;
    }
}

// ---------------- prepass: w = (wq - zp) -> bf16 (exact, |v|<=255) ------------------
__global__ void cvt_w_kernel(const int4* __restrict__ wq, const int* __restrict__ zp,
                             ushort4_t* __restrict__ out) {
    int o = blockIdx.x;
    int z = zp[o];
    const int4* src = wq + (long)o * (K_TOT / 4);
    ushort4_t* dst = out + (long)o * (K_TOT / 4);
    for (int t = threadIdx.x; t < K_TOT / 4; t += blockDim.x) {
        int4 q = src[t];
        ushort4_t r;
        r[0] = f2bf((float)(q.x - z)); r[1] = f2bf((float)(q.y - z));
        r[2] = f2bf((float)(q.z - z)); r[3] = f2bf((float)(q.w - z));
        dst[t] = r;
    }
}

// ================= 256x256 8-phase GEMM, deep-prefetch ledger =======================
// C[M,N] = A[M,K] * B[N,K]^T, epilogue y = scale[n]*acc + bias[n].
// 8 waves (2M x 4N), per-wave 128x64 out; BK=64, 2 K-tiles/iter, 128 KiB LDS dbuf.
// Both B-halves kept in regs -> P4/P8 have no ds_reads; full next-tile (8 loads)
// burst-staged at P4/P8 with vmcnt(8) counted drains: every load has >=4 phases lead.
// Swizzle: LDS dest linear (global_load_lds), 16B-chunk XOR (row&7) applied on the
// GLOBAL source and identically on the ds_read -> conflict-free b128 reads.

template<int MH>
__device__ __forceinline__ void read_a(short8 (&a)[4][2], const unsigned short* Ab,
                                       int fr, int krow) {
    const int sw = fr & 7;
#pragma unroll
    for (int mi = 0; mi < 4; ++mi) {
        const int row = (MH * 4 + mi) * 16 + fr;
#pragma unroll
        for (int kk = 0; kk < 2; ++kk)
            a[mi][kk] = *(const short8*)&Ab[row * 64 + (((kk << 2) | krow) ^ sw) * 8];
    }
}

template<int NH>
__device__ __forceinline__ void read_b(short8 (&b)[2][2], const unsigned short* Bb,
                                       int rb, int fr, int krow) {
    const int sw = fr & 7;
#pragma unroll
    for (int ni = 0; ni < 2; ++ni) {
        const int row = rb + (NH * 2 + ni) * 16 + fr;
#pragma unroll
        for (int kk = 0; kk < 2; ++kk)
            b[ni][kk] = *(const short8*)&Bb[row * 64 + (((kk << 2) | krow) ^ sw) * 8];
    }
}

template<int MH, int NH>
__device__ __forceinline__ void mfma16(f32x4 (&acc)[8][4], short8 (&a)[4][2], short8 (&b)[2][2]) {
    __builtin_amdgcn_s_setprio(1);
#pragma unroll
    for (int kk = 0; kk < 2; ++kk)
#pragma unroll
        for (int mi = 0; mi < 4; ++mi)
#pragma unroll
            for (int ni = 0; ni < 2; ++ni)
                acc[MH * 4 + mi][NH * 2 + ni] = __builtin_amdgcn_mfma_f32_16x16x32_bf16(
                    a[mi][kk], b[ni][kk], acc[MH * 4 + mi][NH * 2 + ni], 0, 0, 0);
    __builtin_amdgcn_s_setprio(0);
}

#define BAR() __builtin_amdgcn_s_barrier()
#define LGKM0() asm volatile("s_waitcnt lgkmcnt(0)" ::: "memory")
#define VMCNT8() asm volatile("s_waitcnt vmcnt(8)" ::: "memory")
#define VMCNT0() asm volatile("s_waitcnt vmcnt(0)" ::: "memory")

__launch_bounds__(512, 2)
__global__ void gemm256_kernel(const unsigned short* __restrict__ A,   // [M][K] bf16
                               const unsigned short* __restrict__ B,   // [N][K] bf16
                               const float* __restrict__ scale,
                               const float* __restrict__ bias,
                               float* __restrict__ C, int nbm) {
    __shared__ unsigned short lds[4][2][128 * 64];   // [buf*2+mat][half][row*64+col] 128 KiB

    const int nbn = N_TOT / 256;                     // 16
    int bid = blockIdx.x;
    const int nwg = gridDim.x;
    if ((nwg & 7) == 0) {                            // T1: bijective XCD swizzle
        const int cpx = nwg >> 3;
        bid = (bid & 7) * cpx + (bid >> 3);
    }
    const int bm = bid / nbn, bn = bid % nbn;

    const int tid = threadIdx.x;
    const int w = tid >> 6, lane = tid & 63;
    const int wr = w >> 2, wc = w & 3;               // 2x4 wave grid
    const int fr = lane & 15, krow = lane >> 4;
    const int brb = (wc & 1) * 64;                   // B row base within half

    const long a_row0 = (long)bm * 256;
    const long b_row0 = (long)bn * 256;

    f32x4 acc[8][4] = {};
    short8 afr[4][2], b0[2][2], b1[2][2];

    // stage one half-tile (128 rows x 64 cols bf16): 2 x global_load_lds / thread,
    // linear LDS dest, inverse-swizzled global source chunk.
    auto stage = [&](int t, int mat, int half) {
        const unsigned short* G = (mat == 0) ? A : B;
        const long row0 = ((mat == 0) ? a_row0 : b_row0) + half * 128;
        unsigned short* lb = &lds[(t & 1) * 2 + mat][half][0];
#pragma unroll
        for (int r = 0; r < 2; ++r) {
            const int ck = w * 2 + r;                       // 1 KiB chunk id 0..15
            const int row = ck * 8 + (lane >> 3);           // 0..127
            const int c = (lane & 7) ^ (row & 7);           // pre-swizzled 16B chunk
            const unsigned short* g = G + (row0 + row) * K_TOT + (long)t * 64 + c * 8;
            __builtin_amdgcn_global_load_lds(
                (const __attribute__((address_space(1))) void*)g,
                (__attribute__((address_space(3))) void*)(lb + ck * 512), 16, 0, 0);
        }
    };
    auto stage_tile = [&](int t) {                   // full tile: 8 global_load_lds
        stage(t, 0, 0); stage(t, 0, 1); stage(t, 1, 0); stage(t, 1, 1);
    };

    const unsigned short* Ab0 = &lds[0][wr][0];
    const unsigned short* Bb0 = &lds[1][wc >> 1][0];
    const unsigned short* Ab1 = &lds[2][wr][0];
    const unsigned short* Bb1 = &lds[3][wc >> 1][0];

    // prologue: tiles 0 and 1 fully issued (16 loads); drain tile 0 only.
    stage_tile(0);
    stage_tile(1);
    VMCNT8();
    BAR();

    const int NIT = K_TOT / 128;                     // 32
#pragma unroll 1
    for (int it = 0; it < NIT; ++it) {
        const bool nl = (it != NIT - 1);
        const int t2 = 2 * it + 2, t3 = 2 * it + 3;

        // ---------- buf0 : tile 2it ----------
        // P1 q(0,0): read a0, b0
        read_a<0>(afr, Ab0, fr, krow);
        read_b<0>(b0, Bb0, brb, fr, krow);
        BAR(); LGKM0();
        mfma16<0, 0>(acc, afr, b0);
        BAR();
        // P2 q(0,1): read b1
        read_b<1>(b1, Bb0, brb, fr, krow);
        BAR(); LGKM0();
        mfma16<0, 1>(acc, afr, b1);
        BAR();
        // P3 q(1,1): read a1
        read_a<1>(afr, Ab0, fr, krow);
        BAR(); LGKM0();
        mfma16<1, 1>(acc, afr, b1);
        BAR();
        // P4 q(1,0): no reads; burst-stage tile t2 into buf0; drain tile t1
        if (nl) stage_tile(t2);
        BAR();
        mfma16<1, 0>(acc, afr, b0);
        if (nl) { VMCNT8(); } else { VMCNT0(); }
        BAR();

        // ---------- buf1 : tile 2it+1 ----------
        // P5 q(0,0)
        read_a<0>(afr, Ab1, fr, krow);
        read_b<0>(b0, Bb1, brb, fr, krow);
        BAR(); LGKM0();
        mfma16<0, 0>(acc, afr, b0);
        BAR();
        // P6 q(0,1)
        read_b<1>(b1, Bb1, brb, fr, krow);
        BAR(); LGKM0();
        mfma16<0, 1>(acc, afr, b1);
        BAR();
        // P7 q(1,1)
        read_a<1>(afr, Ab1, fr, krow);
        BAR(); LGKM0();
        mfma16<1, 1>(acc, afr, b1);
        BAR();
        // P8 q(1,0): burst-stage tile t3 into buf1; drain tile t2
        if (nl) stage_tile(t3);
        BAR();
        mfma16<1, 0>(acc, afr, b0);
        if (nl) { VMCNT8(); }
        BAR();
    }

    // epilogue: y = scale[col]*acc + bias[col]
#pragma unroll
    for (int n = 0; n < 4; ++n) {
        const int col = (int)b_row0 + wc * 64 + n * 16 + fr;
        const float s = scale[col], bb = bias[col];
#pragma unroll
        for (int m = 0; m < 8; ++m) {
            const long row0 = a_row0 + wr * 128 + m * 16 + krow * 4;
#pragma unroll
            for (int j = 0; j < 4; ++j)
                C[(row0 + j) * N_TOT + col] = acc[m][n][j] * s + bb;
        }
    }
}

// ---------------- fallback (ws too small / M%256!=0): fp32 tiled GEMM ----------------
__global__ void fallback_kernel(const float* __restrict__ x, const int* __restrict__ wq,
                                const int* __restrict__ zp, const float* __restrict__ sc,
                                const float* __restrict__ bs, float* __restrict__ y) {
    __shared__ float xs[32][33];
    __shared__ float ws[32][33];
    int bm = blockIdx.y, bn = blockIdx.x;
    int tid = threadIdx.x;
    int r = tid >> 5, c = tid & 31;
    float acc[4] = {0.f, 0.f, 0.f, 0.f};
    for (int k0 = 0; k0 < K_TOT; k0 += 32) {
        for (int t = tid; t < 32 * 32; t += 256) {
            int rr = t >> 5, cc = t & 31;
            xs[rr][cc] = x[(long)(bm * 32 + rr) * K_TOT + k0 + cc];
            int o = bn * 32 + rr;
            ws[rr][cc] = (float)(wq[(long)o * K_TOT + k0 + cc] - zp[o]);
        }
        __syncthreads();
#pragma unroll
        for (int kk = 0; kk < 32; ++kk) {
            float wv = ws[c][kk];
#pragma unroll
            for (int j = 0; j < 4; ++j) acc[j] += xs[r + 8 * j][kk] * wv;
        }
        __syncthreads();
    }
    int o = bn * 32 + c;
    float s = sc[o], b = bs[o];
#pragma unroll
    for (int j = 0; j < 4; ++j)
        y[(long)(bm * 32 + r + 8 * j) * N_TOT + o] = acc[j] * s + b;
}

extern "C" void kernel_launch(void* const* d_in, const int* in_sizes, int n_in,
                              void* d_out, int out_size, void* d_ws, size_t ws_size,
                              hipStream_t stream) {
    const float* x = (const float*)d_in[0];
    const int* wq = (const int*)d_in[1];
    const int* zp = (const int*)d_in[2];
    const float* sc = (const float*)d_in[3];
    const float* bs = (const float*)d_in[4];
    float* y = (float*)d_out;

    const long M = (long)in_sizes[0] / K_TOT;   // 8192

    size_t xb_bytes = (size_t)M * K_TOT * 2;          // 67 MB
    size_t wb_bytes = (size_t)N_TOT * K_TOT * 2;      // 33.5 MB

    if (ws_size >= xb_bytes + wb_bytes && (M & 255) == 0) {
        unsigned short* xb = (unsigned short*)d_ws;
        unsigned short* wb = (unsigned short*)((char*)d_ws + xb_bytes);
        long n8 = M * K_TOT / 8;
        cvt_x_kernel<<<2048, 256, 0, stream>>>((const float4*)x, (ushort8_t*)xb, n8);
        cvt_w_kernel<<<N_TOT, 256, 0, stream>>>((const int4*)wq, zp, (ushort4_t*)wb);
        dim3 grid((unsigned)((M / 256) * (N_TOT / 256)));   // 512
        gemm256_kernel<<<grid, 512, 0, stream>>>(xb, wb, sc, bs, y, (int)(M / 256));
    } else {
        dim3 grid(N_TOT / 32, (unsigned)(M / 32));
        fallback_kernel<<<grid, 256, 0, stream>>>(x, wq, zp, sc, bs, y);
    }
}

// Round 4
// 300.836 us; speedup vs baseline: 1.0751x; 1.0751x over previous
//
#include <hip/hip_runtime.h>
#include <hip/hip_bf16.h>
#include <stdint.h>

typedef __attribute__((ext_vector_type(8))) short short8;           // 8 bf16 (4 VGPR) MFMA frag
typedef __attribute__((ext_vector_type(4))) float f32x4;            // MFMA acc
typedef __attribute__((ext_vector_type(4))) unsigned short ushort4_t;
typedef __attribute__((ext_vector_type(8))) unsigned short ushort8_t;

#define K_TOT 4096
#define N_TOT 4096

static __device__ __forceinline__ unsigned short f2bf(float f) {
    union { float f; unsigned int u; } v; v.f = f;
    unsigned int u = v.u;
    u += 0x7fffu + ((u >> 16) & 1u);   // round-to-nearest-even
    return (unsigned short)(u >> 16);
}

// ---------------- prepass: x fp32 -> bf16 -------------------------------------------
__global__ void cvt_x_kernel(const float4* __restrict__ x, ushort8_t* __restrict__ out, long n8) {
    long i = (long)blockIdx.x * blockDim.x + threadIdx.x;
    long stride = (long)gridDim.x * blockDim.x;
    for (; i < n8; i += stride) {
        float4 a = x[2 * i], b = x[2 * i + 1];
        ushort8_t r;
        r[0] = f2bf(a.x); r[1] = f2bf(a.y); r[2] = f2bf(a.z); r[3] = f2bf(a.w);
        r[4] = f2bf(b.x); r[5] = f2bf(b.y); r[6] = f2bf(b.z); r[7] = f2bf(b.w);
        out[i] = r;
    }
}

// ---------------- prepass: w = (wq - zp) -> bf16 (exact, |v|<=255) ------------------
__global__ void cvt_w_kernel(const int4* __restrict__ wq, const int* __restrict__ zp,
                             ushort4_t* __restrict__ out) {
    int o = blockIdx.x;
    int z = zp[o];
    const int4* src = wq + (long)o * (K_TOT / 4);
    ushort4_t* dst = out + (long)o * (K_TOT / 4);
    for (int t = threadIdx.x; t < K_TOT / 4; t += blockDim.x) {
        int4 q = src[t];
        ushort4_t r;
        r[0] = f2bf((float)(q.x - z)); r[1] = f2bf((float)(q.y - z));
        r[2] = f2bf((float)(q.z - z)); r[3] = f2bf((float)(q.w - z));
        dst[t] = r;
    }
}

// ================= 256x256 8-phase GEMM, fine interleave + 2-phase-lead ledger =======
// C[M,N] = A[M,K] * B[N,K]^T, epilogue y = scale[n]*acc + bias[n].
// 8 waves (2M x 4N), per-wave 128x64 out; BK=64, 2 K-tiles/iter, 128 KiB LDS dbuf.
// Exactly 1 half-tile (2 global_load_lds) staged per phase (m196: the fine interleave
// is the lever); B-halves kept in regs so buf.B frees after P2/P6, letting the ledger
// run 2 phases earlier than R2. Counted vmcnt(4) at P4/P8 only; never 0 mid-loop.
// Swizzle: LDS dest linear (global_load_lds), 16B-chunk XOR (row&7) applied on the
// GLOBAL source and identically on the ds_read -> conflict-free b128 reads.

template<int MH>
__device__ __forceinline__ void read_a(short8 (&a)[4][2], const unsigned short* Ab,
                                       int fr, int krow) {
    const int sw = fr & 7;
#pragma unroll
    for (int mi = 0; mi < 4; ++mi) {
        const int row = (MH * 4 + mi) * 16 + fr;
#pragma unroll
        for (int kk = 0; kk < 2; ++kk)
            a[mi][kk] = *(const short8*)&Ab[row * 64 + (((kk << 2) | krow) ^ sw) * 8];
    }
}

template<int NH>
__device__ __forceinline__ void read_b(short8 (&b)[2][2], const unsigned short* Bb,
                                       int rb, int fr, int krow) {
    const int sw = fr & 7;
#pragma unroll
    for (int ni = 0; ni < 2; ++ni) {
        const int row = rb + (NH * 2 + ni) * 16 + fr;
#pragma unroll
        for (int kk = 0; kk < 2; ++kk)
            b[ni][kk] = *(const short8*)&Bb[row * 64 + (((kk << 2) | krow) ^ sw) * 8];
    }
}

template<int MH, int NH>
__device__ __forceinline__ void mfma16(f32x4 (&acc)[8][4], short8 (&a)[4][2], short8 (&b)[2][2]) {
    __builtin_amdgcn_s_setprio(1);
#pragma unroll
    for (int kk = 0; kk < 2; ++kk)
#pragma unroll
        for (int mi = 0; mi < 4; ++mi)
#pragma unroll
            for (int ni = 0; ni < 2; ++ni)
                acc[MH * 4 + mi][NH * 2 + ni] = __builtin_amdgcn_mfma_f32_16x16x32_bf16(
                    a[mi][kk], b[ni][kk], acc[MH * 4 + mi][NH * 2 + ni], 0, 0, 0);
    __builtin_amdgcn_s_setprio(0);
}

#define BAR() __builtin_amdgcn_s_barrier()
#define LGKM0() asm volatile("s_waitcnt lgkmcnt(0)" ::: "memory")
#define VMCNT4() asm volatile("s_waitcnt vmcnt(4)" ::: "memory")
#define VMCNT0() asm volatile("s_waitcnt vmcnt(0)" ::: "memory")

__launch_bounds__(512, 2)
__global__ void gemm256_kernel(const unsigned short* __restrict__ A,   // [M][K] bf16
                               const unsigned short* __restrict__ B,   // [N][K] bf16
                               const float* __restrict__ scale,
                               const float* __restrict__ bias,
                               float* __restrict__ C, int nbm) {
    __shared__ unsigned short lds[4][2][128 * 64];   // [buf*2+mat][half][row*64+col] 128 KiB

    const int nbn = N_TOT / 256;                     // 16
    int bid = blockIdx.x;
    const int nwg = gridDim.x;
    if ((nwg & 7) == 0) {                            // T1: bijective XCD swizzle
        const int cpx = nwg >> 3;
        bid = (bid & 7) * cpx + (bid >> 3);
    }
    const int bm = bid / nbn, bn = bid % nbn;

    const int tid = threadIdx.x;
    const int w = tid >> 6, lane = tid & 63;
    const int wr = w >> 2, wc = w & 3;               // 2x4 wave grid
    const int fr = lane & 15, krow = lane >> 4;
    const int brb = (wc & 1) * 64;                   // B row base within half

    const long a_row0 = (long)bm * 256;
    const long b_row0 = (long)bn * 256;

    f32x4 acc[8][4] = {};
    short8 afr[4][2], b0[2][2], b1[2][2];

    // stage one half-tile (128 rows x 64 cols bf16): 2 x global_load_lds / thread,
    // linear LDS dest, inverse-swizzled global source chunk.
    auto stage = [&](int t, int mat, int half) {
        const unsigned short* G = (mat == 0) ? A : B;
        const long row0 = ((mat == 0) ? a_row0 : b_row0) + half * 128;
        unsigned short* lb = &lds[(t & 1) * 2 + mat][half][0];
#pragma unroll
        for (int r = 0; r < 2; ++r) {
            const int ck = w * 2 + r;                       // 1 KiB chunk id 0..15
            const int row = ck * 8 + (lane >> 3);           // 0..127
            const int c = (lane & 7) ^ (row & 7);           // pre-swizzled 16B chunk
            const unsigned short* g = G + (row0 + row) * K_TOT + (long)t * 64 + c * 8;
            __builtin_amdgcn_global_load_lds(
                (const __attribute__((address_space(1))) void*)g,
                (__attribute__((address_space(3))) void*)(lb + ck * 512), 16, 0, 0);
        }
    };

    const unsigned short* Ab0 = &lds[0][wr][0];
    const unsigned short* Bb0 = &lds[1][wc >> 1][0];
    const unsigned short* Ab1 = &lds[2][wr][0];
    const unsigned short* Bb1 = &lds[3][wc >> 1][0];

    // prologue: t0 fully + t1.B (mimics steady state at P1 entry); drain t0 only.
    stage(0, 0, 0); stage(0, 0, 1); stage(0, 1, 0); stage(0, 1, 1);
    stage(1, 1, 0); stage(1, 1, 1);
    VMCNT4();
    BAR();

    const int NIT = K_TOT / 128;                     // 32 iters, 64 K-tiles
#pragma unroll 1
    for (int it = 0; it < NIT; ++it) {
        const bool nl = (it != NIT - 1);
        const int t1 = 2 * it + 1, t2 = 2 * it + 2, t3 = 2 * it + 3;

        // ---------- buf0 : tile 2it ----------
        // P1 q(0,0): read a0,b0 | stage t1.A.h0
        read_a<0>(afr, Ab0, fr, krow);
        read_b<0>(b0, Bb0, brb, fr, krow);
        stage(t1, 0, 0);
        BAR(); LGKM0();
        mfma16<0, 0>(acc, afr, b0);
        BAR();
        // P2 q(0,1): read b1 | stage t1.A.h1
        read_b<1>(b1, Bb0, brb, fr, krow);
        stage(t1, 0, 1);
        BAR(); LGKM0();
        mfma16<0, 1>(acc, afr, b1);
        BAR();
        // P3 q(1,1): read a1 | stage t2.B.h0 (buf0.B free after P2)
        read_a<1>(afr, Ab0, fr, krow);
        if (nl) stage(t2, 1, 0);
        BAR(); LGKM0();
        mfma16<1, 1>(acc, afr, b1);
        BAR();
        // P4 q(1,0): no ds_reads | stage t2.B.h1 | drain t1 (vmcnt 4: leaves t2.B)
        if (nl) stage(t2, 1, 1);
        BAR();
        mfma16<1, 0>(acc, afr, b0);
        if (nl) { VMCNT4(); } else { VMCNT0(); }
        BAR();

        // ---------- buf1 : tile 2it+1 ----------
        // P5 q(0,0) | stage t2.A.h0 (buf0.A free after P3)
        read_a<0>(afr, Ab1, fr, krow);
        read_b<0>(b0, Bb1, brb, fr, krow);
        if (nl) stage(t2, 0, 0);
        BAR(); LGKM0();
        mfma16<0, 0>(acc, afr, b0);
        BAR();
        // P6 q(0,1) | stage t2.A.h1
        read_b<1>(b1, Bb1, brb, fr, krow);
        if (nl) stage(t2, 0, 1);
        BAR(); LGKM0();
        mfma16<0, 1>(acc, afr, b1);
        BAR();
        // P7 q(1,1) | stage t3.B.h0 (buf1.B free after P6)
        read_a<1>(afr, Ab1, fr, krow);
        if (nl) stage(t3, 1, 0);
        BAR(); LGKM0();
        mfma16<1, 1>(acc, afr, b1);
        BAR();
        // P8 q(1,0): no ds_reads | stage t3.B.h1 | drain t2 (vmcnt 4: leaves t3.B)
        if (nl) stage(t3, 1, 1);
        BAR();
        mfma16<1, 0>(acc, afr, b0);
        if (nl) { VMCNT4(); }
        BAR();
    }

    // epilogue: y = scale[col]*acc + bias[col]
#pragma unroll
    for (int n = 0; n < 4; ++n) {
        const int col = (int)b_row0 + wc * 64 + n * 16 + fr;
        const float s = scale[col], bb = bias[col];
#pragma unroll
        for (int m = 0; m < 8; ++m) {
            const long row0 = a_row0 + wr * 128 + m * 16 + krow * 4;
#pragma unroll
            for (int j = 0; j < 4; ++j)
                C[(row0 + j) * N_TOT + col] = acc[m][n][j] * s + bb;
        }
    }
}

// ---------------- fallback (ws too small / M%256!=0): fp32 tiled GEMM ----------------
__global__ void fallback_kernel(const float* __restrict__ x, const int* __restrict__ wq,
                                const int* __restrict__ zp, const float* __restrict__ sc,
                                const float* __restrict__ bs, float* __restrict__ y) {
    __shared__ float xs[32][33];
    __shared__ float ws[32][33];
    int bm = blockIdx.y, bn = blockIdx.x;
    int tid = threadIdx.x;
    int r = tid >> 5, c = tid & 31;
    float acc[4] = {0.f, 0.f, 0.f, 0.f};
    for (int k0 = 0; k0 < K_TOT; k0 += 32) {
        for (int t = tid; t < 32 * 32; t += 256) {
            int rr = t >> 5, cc = t & 31;
            xs[rr][cc] = x[(long)(bm * 32 + rr) * K_TOT + k0 + cc];
            int o = bn * 32 + rr;
            ws[rr][cc] = (float)(wq[(long)o * K_TOT + k0 + cc] - zp[o]);
        }
        __syncthreads();
#pragma unroll
        for (int kk = 0; kk < 32; ++kk) {
            float wv = ws[c][kk];
#pragma unroll
            for (int j = 0; j < 4; ++j) acc[j] += xs[r + 8 * j][kk] * wv;
        }
        __syncthreads();
    }
    int o = bn * 32 + c;
    float s = sc[o], b = bs[o];
#pragma unroll
    for (int j = 0; j < 4; ++j)
        y[(long)(bm * 32 + r + 8 * j) * N_TOT + o] = acc[j] * s + b;
}

extern "C" void kernel_launch(void* const* d_in, const int* in_sizes, int n_in,
                              void* d_out, int out_size, void* d_ws, size_t ws_size,
                              hipStream_t stream) {
    const float* x = (const float*)d_in[0];
    const int* wq = (const int*)d_in[1];
    const int* zp = (const int*)d_in[2];
    const float* sc = (const float*)d_in[3];
    const float* bs = (const float*)d_in[4];
    float* y = (float*)d_out;

    const long M = (long)in_sizes[0] / K_TOT;   // 8192

    size_t xb_bytes = (size_t)M * K_TOT * 2;          // 67 MB
    size_t wb_bytes = (size_t)N_TOT * K_TOT * 2;      // 33.5 MB

    if (ws_size >= xb_bytes + wb_bytes && (M & 255) == 0) {
        unsigned short* xb = (unsigned short*)d_ws;
        unsigned short* wb = (unsigned short*)((char*)d_ws + xb_bytes);
        long n8 = M * K_TOT / 8;
        cvt_x_kernel<<<2048, 256, 0, stream>>>((const float4*)x, (ushort8_t*)xb, n8);
        cvt_w_kernel<<<N_TOT, 256, 0, stream>>>((const int4*)wq, zp, (ushort4_t*)wb);
        dim3 grid((unsigned)((M / 256) * (N_TOT / 256)));   // 512
        gemm256_kernel<<<grid, 512, 0, stream>>>(xb, wb, sc, bs, y, (int)(M / 256));
    } else {
        dim3 grid(N_TOT / 32, (unsigned)(M / 32));
        fallback_kernel<<<grid, 256, 0, stream>>>(x, wq, zp, sc, bs, y);
    }
}

// Round 5
// 197.481 us; speedup vs baseline: 1.6378x; 1.5234x over previous
//
#include <hip/hip_runtime.h>
#include <hip/hip_bf16.h>
#include <stdint.h>

typedef __attribute__((ext_vector_type(4))) int i32x4;     // i8 MFMA A/B/C: 4 dwords

#define K_TOT 4096
#define N_TOT 4096

// ---------------- prepass 1: per-row symmetric quant x fp32 -> i8 -------------------
// one wave per row: 64 floats/lane in regs, absmax shuffle-reduce, quantize, pack,
// emit packed dwords + s_row (= amax/127) + integer qsum (exact).
__global__ __launch_bounds__(512) void quant_x_kernel(const float4* __restrict__ x4,
                                                      unsigned int* __restrict__ xq_dw,
                                                      float* __restrict__ s_row,
                                                      int* __restrict__ qsum_row) {
    const int wave = threadIdx.x >> 6, lane = threadIdx.x & 63;
    const long row = (long)blockIdx.x * 8 + wave;
    const float4* xr = x4 + row * (K_TOT / 4);

    float4 v[16];
    float amax = 0.f;
#pragma unroll
    for (int i = 0; i < 16; ++i) {
        v[i] = xr[lane + i * 64];
        amax = fmaxf(amax, fmaxf(fmaxf(fabsf(v[i].x), fabsf(v[i].y)),
                                 fmaxf(fabsf(v[i].z), fabsf(v[i].w))));
    }
#pragma unroll
    for (int off = 32; off; off >>= 1) amax = fmaxf(amax, __shfl_xor(amax, off));
    amax = fmaxf(amax, 1e-30f);
    const float inv = 127.0f / amax;

    int qsum = 0;
    unsigned int* out = xq_dw + row * (K_TOT / 4);
#pragma unroll
    for (int i = 0; i < 16; ++i) {
        int q0 = (int)rintf(v[i].x * inv), q1 = (int)rintf(v[i].y * inv);
        int q2 = (int)rintf(v[i].z * inv), q3 = (int)rintf(v[i].w * inv);
        qsum += q0 + q1 + q2 + q3;
        out[lane + i * 64] = (unsigned int)(q0 & 255) | ((unsigned int)(q1 & 255) << 8) |
                             ((unsigned int)(q2 & 255) << 16) | ((unsigned int)(q3 & 255) << 24);
    }
#pragma unroll
    for (int off = 32; off; off >>= 1) qsum += __shfl_xor(qsum, off);
    if (lane == 0) { s_row[row] = amax / 127.0f; qsum_row[row] = qsum; }
}

// ---------------- prepass 2: w8 = (q - 128) as i8 (exact; zp folded into epilogue) --
__global__ void pack_w_kernel(const int4* __restrict__ wq, unsigned int* __restrict__ w8) {
    const long o = blockIdx.x;
    const int4* src = wq + o * (K_TOT / 4);
    unsigned int* dst = w8 + o * (K_TOT / 4);
    for (int t = threadIdx.x; t < K_TOT / 4; t += blockDim.x) {
        int4 q = src[t];
        dst[t] = (unsigned int)((q.x - 128) & 255) | ((unsigned int)((q.y - 128) & 255) << 8) |
                 ((unsigned int)((q.z - 128) & 255) << 16) | ((unsigned int)((q.w - 128) & 255) << 24);
    }
}

// ================= 256x256 8-phase i8 GEMM (R4 skeleton, 2x-rate pipe) ==============
// D[M,N](i32) = Xq[M,K](i8) * W8[N,K](i8)^T via mfma_i32_16x16x64_i8 (K=64/instr).
// 8 waves (2M x 4N), per-wave 128x64; BK=64, 2 K-tiles/iter, 64 KiB LDS dbuf.
// epilogue: y = (sc[n]*s[m]) * (acc + (128-zp[n])*qsum[m]) + bias[n].
// Swizzle (64 B rows, 4x16B chunks): LDS dest linear (global_load_lds), chunk XOR
// ((row>>1)&3) on global source and identically on ds_read -> <=2-way (free).
// Ledger: 1 half-tile stage (1 load/thread) per phase; counted vmcnt(2) at P4/P8.

template<int MH>
__device__ __forceinline__ void read_a8(i32x4 (&a)[4], const char* Ab, int wr, int fr, int kg) {
    const int sw = (fr >> 1) & 3;
#pragma unroll
    for (int mi = 0; mi < 4; ++mi) {
        const int row = wr * 128 + (MH * 4 + mi) * 16 + fr;
        a[mi] = *(const i32x4*)(Ab + row * 64 + ((kg ^ sw) << 4));
    }
}

template<int NH>
__device__ __forceinline__ void read_b8(i32x4 (&b)[2], const char* Bb, int rb, int fr, int kg) {
    const int sw = (fr >> 1) & 3;
#pragma unroll
    for (int ni = 0; ni < 2; ++ni) {
        const int row = rb + (NH * 2 + ni) * 16 + fr;
        b[ni] = *(const i32x4*)(Bb + row * 64 + ((kg ^ sw) << 4));
    }
}

template<int MH, int NH>
__device__ __forceinline__ void mfma8(i32x4 (&acc)[8][4], i32x4 (&a)[4], i32x4 (&b)[2]) {
    __builtin_amdgcn_s_setprio(1);
#pragma unroll
    for (int mi = 0; mi < 4; ++mi)
#pragma unroll
        for (int ni = 0; ni < 2; ++ni)
            acc[MH * 4 + mi][NH * 2 + ni] = __builtin_amdgcn_mfma_i32_16x16x64_i8(
                a[mi], b[ni], acc[MH * 4 + mi][NH * 2 + ni], 0, 0, 0);
    __builtin_amdgcn_s_setprio(0);
}

#define BAR() __builtin_amdgcn_s_barrier()
#define LGKM0() asm volatile("s_waitcnt lgkmcnt(0)" ::: "memory")
#define VMCNT2() asm volatile("s_waitcnt vmcnt(2)" ::: "memory")
#define VMCNT0() asm volatile("s_waitcnt vmcnt(0)" ::: "memory")

__launch_bounds__(512, 2)
__global__ void gemm256_i8_kernel(const char* __restrict__ Aq,   // [M][K] i8
                                  const char* __restrict__ Bq,   // [N][K] i8
                                  const float* __restrict__ s_row,
                                  const int* __restrict__ qsum_row,
                                  const float* __restrict__ scale,
                                  const int* __restrict__ zp,
                                  const float* __restrict__ bias,
                                  float* __restrict__ C) {
    __shared__ __align__(16) char lds[4][256 * 64];   // [buf*2+mat][row*64+byte] 64 KiB

    const int nbn = N_TOT / 256;                      // 16
    int bid = blockIdx.x;
    const int nwg = gridDim.x;
    if ((nwg & 7) == 0) {                             // T1: bijective XCD swizzle
        const int cpx = nwg >> 3;
        bid = (bid & 7) * cpx + (bid >> 3);
    }
    const int bm = bid / nbn, bn = bid % nbn;

    const int tid = threadIdx.x;
    const int w = tid >> 6, lane = tid & 63;
    const int wr = w >> 2, wc = w & 3;                // 2x4 wave grid
    const int fr = lane & 15, kg = lane >> 4;         // fragment row / k-group
    const int brb = (wc >> 1) * 128 + (wc & 1) * 64;  // B row base (within 256-row tile)

    const long a_row0 = (long)bm * 256;
    const long b_row0 = (long)bn * 256;

    i32x4 acc[8][4] = {};
    i32x4 afr[4], b0[2], b1[2];

    // stage one half-tile (128 rows x 64 B): 1 global_load_lds per thread.
    // wave w covers rows w*16..+15 of the half; LDS dest linear (base + lane*16).
    auto stage = [&](int t, int mat, int half) {
        const char* G = (mat == 0) ? Aq : Bq;
        const long row0 = ((mat == 0) ? a_row0 : b_row0) + half * 128;
        char* lb = &lds[(t & 1) * 2 + mat][half * 8192 + w * 1024];
        const int row = w * 16 + (lane >> 2);               // row within half
        const int c = (lane & 3) ^ (((half * 128 + row) >> 1) & 3);  // pre-swizzled 16B chunk
        const char* g = G + (row0 + row) * K_TOT + (long)t * 64 + c * 16;
        __builtin_amdgcn_global_load_lds(
            (const __attribute__((address_space(1))) void*)g,
            (__attribute__((address_space(3))) void*)lb, 16, 0, 0);
    };

    const char* Ab0 = &lds[0][0];
    const char* Bb0 = &lds[1][0];
    const char* Ab1 = &lds[2][0];
    const char* Bb1 = &lds[3][0];

    // prologue: t0 fully + t1.B; drain t0 (leave t1.B = 2 outstanding).
    stage(0, 0, 0); stage(0, 0, 1); stage(0, 1, 0); stage(0, 1, 1);
    stage(1, 1, 0); stage(1, 1, 1);
    VMCNT2();
    BAR();

    const int NIT = K_TOT / 128;                      // 32 iters, 64 K-tiles
#pragma unroll 1
    for (int it = 0; it < NIT; ++it) {
        const bool nl = (it != NIT - 1);
        const int t1 = 2 * it + 1, t2 = 2 * it + 2, t3 = 2 * it + 3;

        // ---------- buf0 : tile 2it ----------
        // P1 q(0,0): read a0,b0 | stage t1.A.h0
        read_a8<0>(afr, Ab0, wr, fr, kg);
        read_b8<0>(b0, Bb0, brb, fr, kg);
        stage(t1, 0, 0);
        BAR(); LGKM0();
        mfma8<0, 0>(acc, afr, b0);
        BAR();
        // P2 q(0,1): read b1 | stage t1.A.h1
        read_b8<1>(b1, Bb0, brb, fr, kg);
        stage(t1, 0, 1);
        BAR(); LGKM0();
        mfma8<0, 1>(acc, afr, b1);
        BAR();
        // P3 q(1,1): read a1 | stage t2.B.h0 (buf0.B free after P2)
        read_a8<1>(afr, Ab0, wr, fr, kg);
        if (nl) stage(t2, 1, 0);
        BAR(); LGKM0();
        mfma8<1, 1>(acc, afr, b1);
        BAR();
        // P4 q(1,0): no ds_reads | stage t2.B.h1 | drain t1 (vmcnt2 leaves t2.B)
        if (nl) stage(t2, 1, 1);
        BAR();
        mfma8<1, 0>(acc, afr, b0);
        if (nl) { VMCNT2(); } else { VMCNT0(); }
        BAR();

        // ---------- buf1 : tile 2it+1 ----------
        // P5 q(0,0) | stage t2.A.h0 (buf0.A free after P3)
        read_a8<0>(afr, Ab1, wr, fr, kg);
        read_b8<0>(b0, Bb1, brb, fr, kg);
        if (nl) stage(t2, 0, 0);
        BAR(); LGKM0();
        mfma8<0, 0>(acc, afr, b0);
        BAR();
        // P6 q(0,1) | stage t2.A.h1
        read_b8<1>(b1, Bb1, brb, fr, kg);
        if (nl) stage(t2, 0, 1);
        BAR(); LGKM0();
        mfma8<0, 1>(acc, afr, b1);
        BAR();
        // P7 q(1,1) | stage t3.B.h0 (buf1.B free after P6)
        read_a8<1>(afr, Ab1, wr, fr, kg);
        if (nl) stage(t3, 1, 0);
        BAR(); LGKM0();
        mfma8<1, 1>(acc, afr, b1);
        BAR();
        // P8 q(1,0): stage t3.B.h1 | drain t2 (vmcnt2 leaves t3.B)
        if (nl) stage(t3, 1, 1);
        BAR();
        mfma8<1, 0>(acc, afr, b0);
        if (nl) { VMCNT2(); }
        BAR();
    }

    // epilogue: y = (scale[col]*s[row]) * (acc + (128-zp[col])*qsum[row]) + bias[col]
    float scs[4], c1s[4], bbs[4]; int cols[4];
#pragma unroll
    for (int n = 0; n < 4; ++n) {
        cols[n] = (int)b_row0 + wc * 64 + n * 16 + fr;
        scs[n] = scale[cols[n]];
        c1s[n] = (float)(128 - zp[cols[n]]);
        bbs[n] = bias[cols[n]];
    }
#pragma unroll
    for (int m = 0; m < 8; ++m) {
#pragma unroll
        for (int j = 0; j < 4; ++j) {
            const long r = a_row0 + wr * 128 + m * 16 + kg * 4 + j;
            const float sr = s_row[r];
            const float qs = (float)qsum_row[r];
#pragma unroll
            for (int n = 0; n < 4; ++n)
                C[r * N_TOT + cols[n]] = ((float)acc[m][n][j] + c1s[n] * qs) * (scs[n] * sr) + bbs[n];
        }
    }
}

// ---------------- fallback (ws too small / M%256!=0): fp32 tiled GEMM ----------------
__global__ void fallback_kernel(const float* __restrict__ x, const int* __restrict__ wq,
                                const int* __restrict__ zp, const float* __restrict__ sc,
                                const float* __restrict__ bs, float* __restrict__ y) {
    __shared__ float xs[32][33];
    __shared__ float ws[32][33];
    int bm = blockIdx.y, bn = blockIdx.x;
    int tid = threadIdx.x;
    int r = tid >> 5, c = tid & 31;
    float acc[4] = {0.f, 0.f, 0.f, 0.f};
    for (int k0 = 0; k0 < K_TOT; k0 += 32) {
        for (int t = tid; t < 32 * 32; t += 256) {
            int rr = t >> 5, cc = t & 31;
            xs[rr][cc] = x[(long)(bm * 32 + rr) * K_TOT + k0 + cc];
            int o = bn * 32 + rr;
            ws[rr][cc] = (float)(wq[(long)o * K_TOT + k0 + cc] - zp[o]);
        }
        __syncthreads();
#pragma unroll
        for (int kk = 0; kk < 32; ++kk) {
            float wv = ws[c][kk];
#pragma unroll
            for (int j = 0; j < 4; ++j) acc[j] += xs[r + 8 * j][kk] * wv;
        }
        __syncthreads();
    }
    int o = bn * 32 + c;
    float s = sc[o], b = bs[o];
#pragma unroll
    for (int j = 0; j < 4; ++j)
        y[(long)(bm * 32 + r + 8 * j) * N_TOT + o] = acc[j] * s + b;
}

extern "C" void kernel_launch(void* const* d_in, const int* in_sizes, int n_in,
                              void* d_out, int out_size, void* d_ws, size_t ws_size,
                              hipStream_t stream) {
    const float* x = (const float*)d_in[0];
    const int* wq = (const int*)d_in[1];
    const int* zp = (const int*)d_in[2];
    const float* sc = (const float*)d_in[3];
    const float* bs = (const float*)d_in[4];
    float* y = (float*)d_out;

    const long M = (long)in_sizes[0] / K_TOT;   // 8192

    size_t xq_bytes = (size_t)M * K_TOT;              // 33.5 MB
    size_t w8_bytes = (size_t)N_TOT * K_TOT;          // 16.8 MB
    size_t s_bytes = (size_t)M * 4;
    size_t q_bytes = (size_t)M * 4;
    size_t need = xq_bytes + w8_bytes + s_bytes + q_bytes + 256;

    if (ws_size >= need && (M & 255) == 0) {
        char* p = (char*)d_ws;
        char* xq = p;                       p += xq_bytes;
        char* w8 = p;                       p += w8_bytes;
        float* s_row = (float*)p;           p += s_bytes;
        int* qsum_row = (int*)p;

        quant_x_kernel<<<(unsigned)(M / 8), 512, 0, stream>>>(
            (const float4*)x, (unsigned int*)xq, s_row, qsum_row);
        pack_w_kernel<<<N_TOT, 256, 0, stream>>>((const int4*)wq, (unsigned int*)w8);

        dim3 grid((unsigned)((M / 256) * (N_TOT / 256)));   // 512
        gemm256_i8_kernel<<<grid, 512, 0, stream>>>(
            xq, w8, s_row, qsum_row, sc, zp, bs, y);
    } else {
        dim3 grid(N_TOT / 32, (unsigned)(M / 32));
        fallback_kernel<<<grid, 256, 0, stream>>>(x, wq, zp, sc, bs, y);
    }
}

// Round 6
// 193.641 us; speedup vs baseline: 1.6703x; 1.0198x over previous
//
#include <hip/hip_runtime.h>
#include <hip/hip_bf16.h>
#include <stdint.h>

typedef __attribute__((ext_vector_type(4))) int i32x4;     // i8 MFMA A/B/C: 4 dwords

#define K_TOT 4096
#define N_TOT 4096

// ---------------- fused prepass: x-quant (blocks < nqb) + w-pack (rest) -------------
// quant: one wave per row, per-row symmetric i8 quant of x; emits packed dwords,
// s_row (=amax/127), integer qsum (exact). pack: w8 = (q-128) i8, 8 rows/block.
__global__ __launch_bounds__(512) void prep_kernel(const float4* __restrict__ x4,
                                                   unsigned int* __restrict__ xq_dw,
                                                   float* __restrict__ s_row,
                                                   int* __restrict__ qsum_row,
                                                   const int4* __restrict__ wq,
                                                   unsigned int* __restrict__ w8,
                                                   int nqb) {
    const int wave = threadIdx.x >> 6, lane = threadIdx.x & 63;
    if ((int)blockIdx.x < nqb) {
        const long row = (long)blockIdx.x * 8 + wave;
        const float4* xr = x4 + row * (K_TOT / 4);
        float4 v[16];
        float amax = 0.f;
#pragma unroll
        for (int i = 0; i < 16; ++i) {
            v[i] = xr[lane + i * 64];
            amax = fmaxf(amax, fmaxf(fmaxf(fabsf(v[i].x), fabsf(v[i].y)),
                                     fmaxf(fabsf(v[i].z), fabsf(v[i].w))));
        }
#pragma unroll
        for (int off = 32; off; off >>= 1) amax = fmaxf(amax, __shfl_xor(amax, off));
        amax = fmaxf(amax, 1e-30f);
        const float inv = 127.0f / amax;
        int qsum = 0;
        unsigned int* out = xq_dw + row * (K_TOT / 4);
#pragma unroll
        for (int i = 0; i < 16; ++i) {
            int q0 = (int)rintf(v[i].x * inv), q1 = (int)rintf(v[i].y * inv);
            int q2 = (int)rintf(v[i].z * inv), q3 = (int)rintf(v[i].w * inv);
            qsum += q0 + q1 + q2 + q3;
            out[lane + i * 64] = (unsigned int)(q0 & 255) | ((unsigned int)(q1 & 255) << 8) |
                                 ((unsigned int)(q2 & 255) << 16) | ((unsigned int)(q3 & 255) << 24);
        }
#pragma unroll
        for (int off = 32; off; off >>= 1) qsum += __shfl_xor(qsum, off);
        if (lane == 0) { s_row[row] = amax / 127.0f; qsum_row[row] = qsum; }
    } else {
        const long o = (long)((int)blockIdx.x - nqb) * 8 + wave;
        const int4* src = wq + o * (K_TOT / 4);
        unsigned int* dst = w8 + o * (K_TOT / 4);
#pragma unroll
        for (int i = 0; i < 16; ++i) {
            int4 q = src[lane + i * 64];
            dst[lane + i * 64] =
                (unsigned int)((q.x - 128) & 255) | ((unsigned int)((q.y - 128) & 255) << 8) |
                ((unsigned int)((q.z - 128) & 255) << 16) | ((unsigned int)((q.w - 128) & 255) << 24);
        }
    }
}

// ================= 256x256 4-phase i8 GEMM =========================================
// D[M,N](i32) = Xq[M,K](i8) * W8[N,K](i8)^T via mfma_i32_16x16x64_i8 (K=64/instr).
// 8 waves (2M x 4N), per-wave 128x64; BK=64, 2 K-tiles/iter, 64 KiB LDS dbuf.
// 4 phases/iter (16 MFMA each) to restore per-phase MFMA mass at the i8 rate;
// 2 half-tile stages per phase keeps the fine interleave; counted vmcnt(2) at
// Ph2/Ph4 (issue-order ledger: retires exactly the next-read tile's 4 loads).
// epilogue: y = (sc[n]*s[m]) * (acc + (128-zp[n])*qsum[m]) + bias[n].
// Swizzle (64 B rows, 4x16B chunks): LDS dest linear (global_load_lds), chunk XOR
// ((row>>1)&3) on global source and identically on ds_read -> <=2-way (free).

template<int MH>
__device__ __forceinline__ void read_a8(i32x4 (&a)[4], const char* Ab, int wr, int fr, int kg) {
    const int sw = (fr >> 1) & 3;
#pragma unroll
    for (int mi = 0; mi < 4; ++mi) {
        const int row = wr * 128 + (MH * 4 + mi) * 16 + fr;
        a[mi] = *(const i32x4*)(Ab + row * 64 + ((kg ^ sw) << 4));
    }
}

template<int NH>
__device__ __forceinline__ void read_b8(i32x4 (&b)[2], const char* Bb, int rb, int fr, int kg) {
    const int sw = (fr >> 1) & 3;
#pragma unroll
    for (int ni = 0; ni < 2; ++ni) {
        const int row = rb + (NH * 2 + ni) * 16 + fr;
        b[ni] = *(const i32x4*)(Bb + row * 64 + ((kg ^ sw) << 4));
    }
}

template<int MH, int NH>
__device__ __forceinline__ void mfma8(i32x4 (&acc)[8][4], i32x4 (&a)[4], i32x4 (&b)[2]) {
#pragma unroll
    for (int mi = 0; mi < 4; ++mi)
#pragma unroll
        for (int ni = 0; ni < 2; ++ni)
            acc[MH * 4 + mi][NH * 2 + ni] = __builtin_amdgcn_mfma_i32_16x16x64_i8(
                a[mi], b[ni], acc[MH * 4 + mi][NH * 2 + ni], 0, 0, 0);
}

#define BAR() __builtin_amdgcn_s_barrier()
#define LGKM0() asm volatile("s_waitcnt lgkmcnt(0)" ::: "memory")
#define VMCNT2() asm volatile("s_waitcnt vmcnt(2)" ::: "memory")
#define VMCNT0() asm volatile("s_waitcnt vmcnt(0)" ::: "memory")
#define PRIO1() __builtin_amdgcn_s_setprio(1)
#define PRIO0() __builtin_amdgcn_s_setprio(0)

__launch_bounds__(512, 2)
__global__ void gemm256_i8_kernel(const char* __restrict__ Aq,   // [M][K] i8
                                  const char* __restrict__ Bq,   // [N][K] i8
                                  const float* __restrict__ s_row,
                                  const int* __restrict__ qsum_row,
                                  const float* __restrict__ scale,
                                  const int* __restrict__ zp,
                                  const float* __restrict__ bias,
                                  float* __restrict__ C) {
    __shared__ __align__(16) char lds[4][256 * 64];   // [buf*2+mat][row*64+byte] 64 KiB

    const int nbn = N_TOT / 256;                      // 16
    int bid = blockIdx.x;
    const int nwg = gridDim.x;
    if ((nwg & 7) == 0) {                             // T1: bijective XCD swizzle
        const int cpx = nwg >> 3;
        bid = (bid & 7) * cpx + (bid >> 3);
    }
    const int bm = bid / nbn, bn = bid % nbn;

    const int tid = threadIdx.x;
    const int w = tid >> 6, lane = tid & 63;
    const int wr = w >> 2, wc = w & 3;                // 2x4 wave grid
    const int fr = lane & 15, kg = lane >> 4;         // fragment row / k-group
    const int brb = (wc >> 1) * 128 + (wc & 1) * 64;  // B row base (within 256-row tile)

    const long a_row0 = (long)bm * 256;
    const long b_row0 = (long)bn * 256;

    i32x4 acc[8][4] = {};
    i32x4 afr[4], b0[2], b1[2];

    // stage one half-tile (128 rows x 64 B): 1 global_load_lds per thread.
    auto stage = [&](int t, int mat, int half) {
        const char* G = (mat == 0) ? Aq : Bq;
        const long row0 = ((mat == 0) ? a_row0 : b_row0) + half * 128;
        char* lb = &lds[(t & 1) * 2 + mat][half * 8192 + w * 1024];
        const int row = w * 16 + (lane >> 2);               // row within half
        const int c = (lane & 3) ^ (((half * 128 + row) >> 1) & 3);  // pre-swizzled 16B chunk
        const char* g = G + (row0 + row) * K_TOT + (long)t * 64 + c * 16;
        __builtin_amdgcn_global_load_lds(
            (const __attribute__((address_space(1))) void*)g,
            (__attribute__((address_space(3))) void*)lb, 16, 0, 0);
    };

    const char* Ab0 = &lds[0][0];
    const char* Bb0 = &lds[1][0];
    const char* Ab1 = &lds[2][0];
    const char* Bb1 = &lds[3][0];

    // prologue: t0 fully + t1.B; drain t0 (leave t1.B = 2 outstanding).
    stage(0, 0, 0); stage(0, 0, 1); stage(0, 1, 0); stage(0, 1, 1);
    stage(1, 1, 0); stage(1, 1, 1);
    VMCNT2();
    BAR();

    const int NIT = K_TOT / 128;                      // 32 iters, 64 K-tiles
#pragma unroll 1
    for (int it = 0; it < NIT; ++it) {
        const bool nl = (it != NIT - 1);
        const int t1 = 2 * it + 1, t2 = 2 * it + 2, t3 = 2 * it + 3;

        // ---- Ph1 (buf0, q(0,*)): read a0,b0,b1 | stage t1.A.h0+h1 ----
        read_a8<0>(afr, Ab0, wr, fr, kg);
        read_b8<0>(b0, Bb0, brb, fr, kg);
        read_b8<1>(b1, Bb0, brb, fr, kg);
        stage(t1, 0, 0); stage(t1, 0, 1);
        BAR(); LGKM0();
        PRIO1(); mfma8<0, 0>(acc, afr, b0); mfma8<0, 1>(acc, afr, b1); PRIO0();
        BAR();
        // ---- Ph2 (buf0, q(1,*)): read a1 | stage t2.B.h0+h1 | drain t1 ----
        read_a8<1>(afr, Ab0, wr, fr, kg);
        if (nl) { stage(t2, 1, 0); stage(t2, 1, 1); }
        BAR(); LGKM0();
        PRIO1(); mfma8<1, 1>(acc, afr, b1); mfma8<1, 0>(acc, afr, b0); PRIO0();
        if (nl) { VMCNT2(); } else { VMCNT0(); }      // retires t1.B + t1.A
        BAR();
        // ---- Ph3 (buf1, q(0,*)): read a0,b0,b1 | stage t2.A.h0+h1 ----
        read_a8<0>(afr, Ab1, wr, fr, kg);
        read_b8<0>(b0, Bb1, brb, fr, kg);
        read_b8<1>(b1, Bb1, brb, fr, kg);
        if (nl) { stage(t2, 0, 0); stage(t2, 0, 1); }
        BAR(); LGKM0();
        PRIO1(); mfma8<0, 0>(acc, afr, b0); mfma8<0, 1>(acc, afr, b1); PRIO0();
        BAR();
        // ---- Ph4 (buf1, q(1,*)): read a1 | stage t3.B.h0+h1 | drain t2 ----
        read_a8<1>(afr, Ab1, wr, fr, kg);
        if (nl) { stage(t3, 1, 0); stage(t3, 1, 1); }
        BAR(); LGKM0();
        PRIO1(); mfma8<1, 1>(acc, afr, b1); mfma8<1, 0>(acc, afr, b0); PRIO0();
        if (nl) { VMCNT2(); }                          // retires t2.B + t2.A
        BAR();
    }

    // epilogue: y = (scale[col]*s[row]) * (acc + (128-zp[col])*qsum[row]) + bias[col]
    float scs[4], c1s[4], bbs[4]; int cols[4];
#pragma unroll
    for (int n = 0; n < 4; ++n) {
        cols[n] = (int)b_row0 + wc * 64 + n * 16 + fr;
        scs[n] = scale[cols[n]];
        c1s[n] = (float)(128 - zp[cols[n]]);
        bbs[n] = bias[cols[n]];
    }
#pragma unroll
    for (int m = 0; m < 8; ++m) {
#pragma unroll
        for (int j = 0; j < 4; ++j) {
            const long r = a_row0 + wr * 128 + m * 16 + kg * 4 + j;
            const float sr = s_row[r];
            const float qs = (float)qsum_row[r];
#pragma unroll
            for (int n = 0; n < 4; ++n)
                C[r * N_TOT + cols[n]] = ((float)acc[m][n][j] + c1s[n] * qs) * (scs[n] * sr) + bbs[n];
        }
    }
}

// ---------------- fallback (ws too small / M%256!=0): fp32 tiled GEMM ----------------
__global__ void fallback_kernel(const float* __restrict__ x, const int* __restrict__ wq,
                                const int* __restrict__ zp, const float* __restrict__ sc,
                                const float* __restrict__ bs, float* __restrict__ y) {
    __shared__ float xs[32][33];
    __shared__ float ws[32][33];
    int bm = blockIdx.y, bn = blockIdx.x;
    int tid = threadIdx.x;
    int r = tid >> 5, c = tid & 31;
    float acc[4] = {0.f, 0.f, 0.f, 0.f};
    for (int k0 = 0; k0 < K_TOT; k0 += 32) {
        for (int t = tid; t < 32 * 32; t += 256) {
            int rr = t >> 5, cc = t & 31;
            xs[rr][cc] = x[(long)(bm * 32 + rr) * K_TOT + k0 + cc];
            int o = bn * 32 + rr;
            ws[rr][cc] = (float)(wq[(long)o * K_TOT + k0 + cc] - zp[o]);
        }
        __syncthreads();
#pragma unroll
        for (int kk = 0; kk < 32; ++kk) {
            float wv = ws[c][kk];
#pragma unroll
            for (int j = 0; j < 4; ++j) acc[j] += xs[r + 8 * j][kk] * wv;
        }
        __syncthreads();
    }
    int o = bn * 32 + c;
    float s = sc[o], b = bs[o];
#pragma unroll
    for (int j = 0; j < 4; ++j)
        y[(long)(bm * 32 + r + 8 * j) * N_TOT + o] = acc[j] * s + b;
}

extern "C" void kernel_launch(void* const* d_in, const int* in_sizes, int n_in,
                              void* d_out, int out_size, void* d_ws, size_t ws_size,
                              hipStream_t stream) {
    const float* x = (const float*)d_in[0];
    const int* wq = (const int*)d_in[1];
    const int* zp = (const int*)d_in[2];
    const float* sc = (const float*)d_in[3];
    const float* bs = (const float*)d_in[4];
    float* y = (float*)d_out;

    const long M = (long)in_sizes[0] / K_TOT;   // 8192

    size_t xq_bytes = (size_t)M * K_TOT;              // 33.5 MB
    size_t w8_bytes = (size_t)N_TOT * K_TOT;          // 16.8 MB
    size_t s_bytes = (size_t)M * 4;
    size_t q_bytes = (size_t)M * 4;
    size_t need = xq_bytes + w8_bytes + s_bytes + q_bytes + 256;

    if (ws_size >= need && (M & 255) == 0) {
        char* p = (char*)d_ws;
        char* xq = p;                       p += xq_bytes;
        char* w8 = p;                       p += w8_bytes;
        float* s_row = (float*)p;           p += s_bytes;
        int* qsum_row = (int*)p;

        const int nqb = (int)(M / 8);                       // 1024 quant blocks
        const int npb = N_TOT / 8;                          // 512 pack blocks
        prep_kernel<<<nqb + npb, 512, 0, stream>>>(
            (const float4*)x, (unsigned int*)xq, s_row, qsum_row,
            (const int4*)wq, (unsigned int*)w8, nqb);

        dim3 grid((unsigned)((M / 256) * (N_TOT / 256)));   // 512
        gemm256_i8_kernel<<<grid, 512, 0, stream>>>(
            xq, w8, s_row, qsum_row, sc, zp, bs, y);
    } else {
        dim3 grid(N_TOT / 32, (unsigned)(M / 32));
        fallback_kernel<<<grid, 256, 0, stream>>>(x, wq, zp, sc, bs, y);
    }
}